// Round 5
// baseline (1674.688 us; speedup 1.0000x reference)
//
#include <hip/hip_runtime.h>
#include <hip/hip_bf16.h>

#define N_NODES 100000
#define N_EDGES 3200000
#define NB      100
#define NPG     1000
#define EPG     32000    // edges per graph
#define DIN     128
#define DH      64
#define DE      32
#define NCLS    10
#define SCAN_BLOCKS 98   // ceil(100000/1024)

// All per-graph kernels use an XCD-affine swizzle: blocks dispatch round-robin
// over the 8 XCDs (blockIdx % 8), so graph g lives on XCD g%8 and its working
// set stays in ONE XCD's 4MB L2 across the whole pipeline.
// R3 evidence: FETCH_SIZE of k_agg128 dropped 254->38 MB with this swizzle.
// R4 evidence: random L2 row-gathers are latency-bound (166us at 6.7% HBM);
// this round gathers from LDS instead (graph h-slice staged per channel-pass).

// ---------------- CSR build ----------------

__global__ void k_hist(const int* __restrict__ dst, int* __restrict__ cnt) {
    int xcd = blockIdx.x & 7, slot = blockIdx.x >> 3;
    int gi = slot / 125, cb = slot - gi * 125;
    int g = xcd + 8 * gi;
    if (g >= NB) return;
    int i = g * EPG + cb * 256 + threadIdx.x;
    atomicAdd(&cnt[dst[i]], 1);
}

__global__ void k_dinv(const int* __restrict__ cnt, float* __restrict__ dinv) {
    int i = blockIdx.x * 256 + threadIdx.x;
    if (i < N_NODES) dinv[i] = rsqrtf((float)cnt[i] + 2.0f);
}

__global__ void k_scanA(const int* __restrict__ cnt, int* __restrict__ partials) {
    __shared__ int sm[256];
    int b = blockIdx.x, t = threadIdx.x;
    int base = b * 1024 + t * 4;
    int s = 0;
    for (int j = 0; j < 4; j++) {
        int idx = base + j;
        if (idx < N_NODES) s += cnt[idx];
    }
    sm[t] = s; __syncthreads();
    for (int off = 128; off > 0; off >>= 1) {
        if (t < off) sm[t] += sm[t + off];
        __syncthreads();
    }
    if (t == 0) partials[b] = sm[0];
}

__global__ void k_scanB(int* __restrict__ partials, int* __restrict__ rowptr) {
    if (threadIdx.x == 0 && blockIdx.x == 0) {
        int acc = 0;
        for (int i = 0; i < SCAN_BLOCKS; i++) {
            int v = partials[i]; partials[i] = acc; acc += v;
        }
        rowptr[N_NODES] = acc;  // == N_EDGES
    }
}

__global__ void k_scanC(const int* __restrict__ cnt, const int* __restrict__ partials,
                        int* __restrict__ rowptr) {
    __shared__ int sm[256];
    int b = blockIdx.x, t = threadIdx.x;
    int base = b * 1024 + t * 4;
    int v[4]; int s = 0;
    for (int j = 0; j < 4; j++) {
        int idx = base + j;
        v[j] = (idx < N_NODES) ? cnt[idx] : 0;
        s += v[j];
    }
    sm[t] = s; __syncthreads();
    for (int off = 1; off < 256; off <<= 1) {
        int x = 0;
        if (t >= off) x = sm[t - off];
        __syncthreads();
        sm[t] += x;
        __syncthreads();
    }
    int g = partials[b] + (sm[t] - s);
    for (int j = 0; j < 4; j++) {
        int idx = base + j;
        if (idx < N_NODES) { rowptr[idx] = g; g += v[j]; }
    }
}

__global__ void k_scatter(const int* __restrict__ src, const int* __restrict__ dst,
                          const float* __restrict__ dinv, int* __restrict__ fill,
                          int* __restrict__ ssrc, float* __restrict__ scoef) {
    int xcd = blockIdx.x & 7, slot = blockIdx.x >> 3;
    int gi = slot / 125, cb = slot - gi * 125;
    int g = xcd + 8 * gi;
    if (g >= NB) return;
    int i = g * EPG + cb * 256 + threadIdx.x;
    int s = src[i], d = dst[i];
    int pos = atomicAdd(&fill[d], 1);
    ssrc[pos]  = s;
    scoef[pos] = dinv[s] * dinv[d];
}

// ---------------- GEMM 1: h = x @ [W_a1 | W_x1]  (128 -> 128) ----------------

__global__ __launch_bounds__(256) void k_gemm1(const float* __restrict__ x,
                                               const float* __restrict__ Wa,
                                               const float* __restrict__ Wx,
                                               float* __restrict__ h) {
    __shared__ float xs[32][128];
    __shared__ float ws[32][128];
    int xcd = blockIdx.x & 7, slot = blockIdx.x >> 3;
    int g = xcd + 8 * (slot >> 5);
    int chunk = slot & 31;
    if (g >= NB) return;
    int row0 = g * NPG + chunk * 32;
    int t = threadIdx.x;
    for (int i = 0; i < 4; i++) {
        int idx = t + 256 * i;
        int r = idx >> 5, k4 = idx & 31;
        int rr = row0 + r; if (rr >= N_NODES) rr = N_NODES - 1;
        *(float4*)&xs[r][k4 * 4] = *(const float4*)&x[(size_t)rr * 128 + k4 * 4];
    }
    float acc[4][4] = {};
    int rg = t >> 5, cg = t & 31;
    for (int kt = 0; kt < 4; kt++) {
        __syncthreads();
        for (int i = 0; i < 4; i++) {
            int idx = t + 256 * i;
            int kk = idx >> 5, c4 = idx & 31;
            int k = kt * 32 + kk, c = c4 * 4;
            float4 v;
            if (c < 64) v = *(const float4*)&Wa[k * 64 + c];
            else        v = *(const float4*)&Wx[k * 64 + (c - 64)];
            *(float4*)&ws[kk][c] = v;
        }
        __syncthreads();
        for (int kk = 0; kk < 32; kk++) {
            float4 w = *(float4*)&ws[kk][cg * 4];
            float xv[4];
            for (int i = 0; i < 4; i++) xv[i] = xs[rg * 4 + i][kt * 32 + kk];
            for (int i = 0; i < 4; i++) {
                acc[i][0] += xv[i] * w.x; acc[i][1] += xv[i] * w.y;
                acc[i][2] += xv[i] * w.z; acc[i][3] += xv[i] * w.w;
            }
        }
    }
    for (int i = 0; i < 4; i++) {
        int r = row0 + rg * 4 + i;
        if (r < N_NODES)
            *(float4*)&h[(size_t)r * 128 + cg * 4] =
                make_float4(acc[i][0], acc[i][1], acc[i][2], acc[i][3]);
    }
}

// ---------------- Aggregation via LDS-resident graph slice ----------------
// Block = (graph g, channel-pass p of 16 ch). Stage h[g's 1000 rows][16 ch]
// into LDS (64 KB), then CSR-gather from LDS. 4 waves x 250 nodes each;
// within a wave: lane = (quarter q 0..3, channel c 0..15), quarters split the
// edge list 4-way, combined by shfl_xor at the end.

__global__ __launch_bounds__(256) void k_agg128s(const float* __restrict__ h,
                                                 const int* __restrict__ rowptr,
                                                 const int* __restrict__ ssrc,
                                                 const float* __restrict__ scoef,
                                                 const float* __restrict__ dinv,
                                                 const float* __restrict__ ba,
                                                 const float* __restrict__ bx,
                                                 float* __restrict__ outB) {
    __shared__ float hs[NPG * 16];   // 64000 B
    int xcd = blockIdx.x & 7, slot = blockIdx.x >> 3;
    int gi = slot >> 3, p = slot & 7;     // 8 passes of 16 channels
    int g = xcd + 8 * gi;
    if (g >= NB) return;
    int t = threadIdx.x;
    int rbase = g * NPG;
    for (int i = t; i < NPG * 4; i += 256) {
        int r = i >> 2, c4 = i & 3;
        *(float4*)&hs[r * 16 + c4 * 4] =
            *(const float4*)&h[(size_t)(rbase + r) * 128 + p * 16 + c4 * 4];
    }
    __syncthreads();
    int wave = t >> 6, lane = t & 63;
    int c = lane & 15, q = lane >> 4;
    int cg = p * 16 + c;
    float bias = (cg < 64) ? ba[cg] : bx[cg - 64];
    int nend = (wave + 1) * 250;
    for (int nl = wave * 250; nl < nend; nl++) {
        int wid = rbase + nl;
        int e0 = rowptr[wid], e1 = rowptr[wid + 1];
        float v = 0.0f;
        for (int e = e0 + q; e < e1; e += 4) {
            int s = ssrc[e] - rbase;
            v += scoef[e] * hs[s * 16 + c];
        }
        v += __shfl_xor(v, 16);
        v += __shfl_xor(v, 32);
        if (q == 0) {
            float di = dinv[wid];
            float r = v + 2.0f * di * di * hs[nl * 16 + c] + bias;
            outB[(size_t)wid * 128 + cg] = fmaxf(r, 0.0f);
        }
    }
}

// Same structure for the 64-channel layer (4 passes). c<32: a-branch
// (+b_a2, no relu); c>=32: x-branch (+b_x2, relu).

__global__ __launch_bounds__(256) void k_agg64s(const float* __restrict__ g2,
                                                const int* __restrict__ rowptr,
                                                const int* __restrict__ ssrc,
                                                const float* __restrict__ scoef,
                                                const float* __restrict__ dinv,
                                                const float* __restrict__ ba2,
                                                const float* __restrict__ bx2,
                                                float* __restrict__ s2) {
    __shared__ float hs[NPG * 16];   // 64000 B
    int xcd = blockIdx.x & 7, slot = blockIdx.x >> 3;
    int gi = slot >> 2, p = slot & 3;     // 4 passes of 16 channels
    int g = xcd + 8 * gi;
    if (g >= NB) return;
    int t = threadIdx.x;
    int rbase = g * NPG;
    for (int i = t; i < NPG * 4; i += 256) {
        int r = i >> 2, c4 = i & 3;
        *(float4*)&hs[r * 16 + c4 * 4] =
            *(const float4*)&g2[(size_t)(rbase + r) * 64 + p * 16 + c4 * 4];
    }
    __syncthreads();
    int wave = t >> 6, lane = t & 63;
    int c = lane & 15, q = lane >> 4;
    int cg = p * 16 + c;
    int nend = (wave + 1) * 250;
    for (int nl = wave * 250; nl < nend; nl++) {
        int wid = rbase + nl;
        int e0 = rowptr[wid], e1 = rowptr[wid + 1];
        float v = 0.0f;
        for (int e = e0 + q; e < e1; e += 4) {
            int s = ssrc[e] - rbase;
            v += scoef[e] * hs[s * 16 + c];
        }
        v += __shfl_xor(v, 16);
        v += __shfl_xor(v, 32);
        if (q == 0) {
            float di = dinv[wid];
            v += 2.0f * di * di * hs[nl * 16 + c];
            if (cg < 32) v += ba2[cg];
            else         v = fmaxf(v + bx2[cg - 32], 0.0f);
            s2[(size_t)wid * 64 + cg] = v;
        }
    }
}

// ---------------- GEMM 2: g2 = [a1|x1] @ blockdiag(W_a2, W_x2) (64ch out) ----------------

__global__ __launch_bounds__(256) void k_gemm2(const float* __restrict__ Bm,
                                               const float* __restrict__ Wa2,
                                               const float* __restrict__ Wx2,
                                               float* __restrict__ g2) {
    __shared__ float xs[64][132];   // padded: breaks 128-stride bank aliasing
    __shared__ float ws[64][68];
    int xcd = blockIdx.x & 7, slot = blockIdx.x >> 3;
    int g = xcd + 8 * (slot >> 4);
    int chunk = slot & 15;
    if (g >= NB) return;
    int row0 = g * NPG + chunk * 64;   // chunk 15 spills into next graph: benign dup
    int t = threadIdx.x;
    for (int i = 0; i < 4; i++) {
        int idx = t + 256 * i;
        int k = idx >> 4, c4 = idx & 15, c = c4 * 4;
        float4 v;
        if (c < 32) v = *(const float4*)&Wa2[k * 32 + c];
        else        v = *(const float4*)&Wx2[k * 32 + (c - 32)];
        *(float4*)&ws[k][c] = v;
    }
    for (int i = 0; i < 8; i++) {
        int idx = t + 256 * i;
        int r = idx >> 5, k4 = idx & 31;
        int rr = row0 + r; if (rr >= N_NODES) rr = N_NODES - 1;
        *(float4*)&xs[r][k4 * 4] = *(const float4*)&Bm[(size_t)rr * 128 + k4 * 4];
    }
    __syncthreads();
    int cg = t & 15, rg = t >> 4;
    int koff = (cg < 8) ? 0 : 64;
    float acc[4][4] = {};
    for (int k = 0; k < 64; k++) {
        float4 w = *(float4*)&ws[k][cg * 4];
        float xv[4];
        for (int i = 0; i < 4; i++) xv[i] = xs[rg * 4 + i][koff + k];
        for (int i = 0; i < 4; i++) {
            acc[i][0] += xv[i] * w.x; acc[i][1] += xv[i] * w.y;
            acc[i][2] += xv[i] * w.z; acc[i][3] += xv[i] * w.w;
        }
    }
    for (int i = 0; i < 4; i++) {
        int r = row0 + rg * 4 + i;
        if (r < N_NODES)
            *(float4*)&g2[(size_t)r * 64 + cg * 4] =
                make_float4(acc[i][0], acc[i][1], acc[i][2], acc[i][3]);
    }
}

// ---------------- Segment softmax stats (cols 0..31), per graph ----------------

__global__ __launch_bounds__(256) void k_smax(const float* __restrict__ s2,
                                              float* __restrict__ gmax,
                                              float* __restrict__ sinv) {
    __shared__ float red[8][32];
    int g = (blockIdx.x & 7) + 8 * (blockIdx.x >> 3);
    if (g >= NB) return;
    int t = threadIdx.x;
    int c = t & 31, sub = t >> 5;
    size_t base = (size_t)g * NPG;
    float m = -1e30f;
    for (int n = sub; n < NPG; n += 8)
        m = fmaxf(m, s2[(base + n) * 64 + c]);
    red[sub][c] = m; __syncthreads();
    if (sub == 0) {
        for (int j = 1; j < 8; j++) m = fmaxf(m, red[j][c]);
        red[0][c] = m;
        gmax[g * 32 + c] = m;
    }
    __syncthreads();
    m = red[0][c];
    __syncthreads();
    float sum = 0.0f;
    for (int n = sub; n < NPG; n += 8)
        sum += expf(s2[(base + n) * 64 + c] - m);
    red[sub][c] = sum; __syncthreads();
    if (sub == 0) {
        for (int j = 1; j < 8; j++) sum += red[j][c];
        sinv[g * 32 + c] = 1.0f / sum;
    }
}

// ---------------- Bilinear pool (spill-free rewrite) ----------------
// Block = (graph, 250-node chunk). Fixed 50-row tiles; exp applied ONCE at
// staging time (was 8x redundant in the inner loop and caused a 256-VGPR
// spill with 251 MB scratch writes -- R4 evidence).

__global__ __launch_bounds__(256) void k_pool(const float* __restrict__ s2,
                                              const float* __restrict__ gmax,
                                              float* __restrict__ prods) {
    __shared__ float ta[50][32];
    __shared__ float tx[50][32];
    __shared__ float gm[32];
    int xcd = blockIdx.x & 7, slot = blockIdx.x >> 3;
    int g = xcd + 8 * (slot >> 2);
    int ch = slot & 3;
    if (g >= NB) return;
    int t = threadIdx.x;
    if (t < 32) gm[t] = gmax[g * 32 + t];
    int e  = t >> 3;            // 0..31 (a-channel)
    int f4 = t & 7;             // group of 4 x-channels
    float a0 = 0.f, a1 = 0.f, a2 = 0.f, a3 = 0.f;
    int base = g * NPG + ch * 250;
    for (int n0 = 0; n0 < 250; n0 += 50) {
        __syncthreads();
        for (int i = t; i < 50 * 16; i += 256) {
            int r = i >> 4, c4 = i & 15;
            float4 v = *(const float4*)&s2[(size_t)(base + n0 + r) * 64 + c4 * 4];
            if (c4 < 8) {
                int cb = c4 * 4;
                v.x = __expf(v.x - gm[cb + 0]);
                v.y = __expf(v.y - gm[cb + 1]);
                v.z = __expf(v.z - gm[cb + 2]);
                v.w = __expf(v.w - gm[cb + 3]);
                *(float4*)&ta[r][cb] = v;
            } else {
                *(float4*)&tx[r][(c4 - 8) * 4] = v;
            }
        }
        __syncthreads();
        #pragma unroll 5
        for (int n = 0; n < 50; n++) {
            float a   = ta[n][e];
            float4 xv = *(float4*)&tx[n][f4 * 4];
            a0 += a * xv.x; a1 += a * xv.y; a2 += a * xv.z; a3 += a * xv.w;
        }
    }
    float* dp = &prods[(size_t)g * 1024 + e * 32 + f4 * 4];
    atomicAdd(dp + 0, a0); atomicAdd(dp + 1, a1);
    atomicAdd(dp + 2, a2); atomicAdd(dp + 3, a3);
}

// ---------------- Head ----------------

__global__ __launch_bounds__(256) void k_head(const float* __restrict__ prods,
                                              const float* __restrict__ sinv,
                                              const float* __restrict__ Wlin,
                                              const float* __restrict__ blin,
                                              float* __restrict__ out) {
    __shared__ float red[4][NCLS];
    int g = (blockIdx.x & 7) + 8 * (blockIdx.x >> 3);
    if (g >= NB) return;
    int t = threadIdx.x;
    float p[NCLS];
    for (int c = 0; c < NCLS; c++) p[c] = 0.0f;
    for (int j = 0; j < 4; j++) {
        int k = t * 4 + j;
        int e = k >> 5;
        float v = prods[(size_t)g * 1024 + k] * sinv[g * 32 + e];
        const float* wrow = &Wlin[(size_t)k * NCLS];
        for (int c = 0; c < NCLS; c++) p[c] += v * wrow[c];
    }
    for (int off = 32; off > 0; off >>= 1)
        for (int c = 0; c < NCLS; c++) p[c] += __shfl_down(p[c], off, 64);
    int wave = t >> 6, lane = t & 63;
    if (lane == 0)
        for (int c = 0; c < NCLS; c++) red[wave][c] = p[c];
    __syncthreads();
    if (t == 0) {
        float logits[NCLS]; float mx = -1e30f;
        for (int c = 0; c < NCLS; c++) {
            logits[c] = red[0][c] + red[1][c] + red[2][c] + red[3][c] + blin[c];
            mx = fmaxf(mx, logits[c]);
        }
        float s = 0.0f;
        for (int c = 0; c < NCLS; c++) { logits[c] = expf(logits[c] - mx); s += logits[c]; }
        float inv = 1.0f / s;
        for (int c = 0; c < NCLS; c++) out[g * NCLS + c] = logits[c] * inv;
    }
}

// ---------------- launch ----------------

extern "C" void kernel_launch(void* const* d_in, const int* in_sizes, int n_in,
                              void* d_out, int out_size, void* d_ws, size_t ws_size,
                              hipStream_t stream) {
    const float* x    = (const float*)d_in[0];
    const int*   ei   = (const int*)d_in[1];
    const float* Wa1  = (const float*)d_in[3];
    const float* ba1  = (const float*)d_in[4];
    const float* Wa2  = (const float*)d_in[5];
    const float* ba2  = (const float*)d_in[6];
    const float* Wx1  = (const float*)d_in[7];
    const float* bx1  = (const float*)d_in[8];
    const float* Wx2  = (const float*)d_in[9];
    const float* bx2  = (const float*)d_in[10];
    const float* Wlin = (const float*)d_in[11];
    const float* blin = (const float*)d_in[12];
    float* out = (float*)d_out;

    char* w = (char*)d_ws;
    auto alloc = [&](size_t bytes) -> void* {
        void* p = (void*)w;
        w += (bytes + 255) & ~(size_t)255;
        return p;
    };
    int*   cnt      = (int*)alloc((N_NODES + 1) * sizeof(int));
    int*   rowptr   = (int*)alloc((N_NODES + 1) * sizeof(int));
    int*   fill     = (int*)alloc(N_NODES * sizeof(int));
    float* dinv     = (float*)alloc(N_NODES * sizeof(float));
    int*   partials = (int*)alloc(1024);
    int*   ssrc     = (int*)alloc((size_t)N_EDGES * sizeof(int));
    float* scoef    = (float*)alloc((size_t)N_EDGES * sizeof(float));
    float* gmax     = (float*)alloc(NB * DE * sizeof(float));
    float* sinv     = (float*)alloc(NB * DE * sizeof(float));
    float* prods    = (float*)alloc((size_t)NB * DE * DE * sizeof(float));
    float* bufA     = (float*)alloc((size_t)N_NODES * 128 * sizeof(float));
    float* bufB     = (float*)alloc((size_t)N_NODES * 128 * sizeof(float));

    const int* srcp = ei;
    const int* dstp = ei + N_EDGES;

    hipMemsetAsync(cnt, 0, (N_NODES + 1) * sizeof(int), stream);
    hipMemsetAsync(prods, 0, (size_t)NB * DE * DE * sizeof(float), stream);
    k_hist<<<8 * 13 * 125, 256, 0, stream>>>(dstp, cnt);
    k_dinv<<<(N_NODES + 255) / 256, 256, 0, stream>>>(cnt, dinv);
    k_scanA<<<SCAN_BLOCKS, 256, 0, stream>>>(cnt, partials);
    k_scanB<<<1, 64, 0, stream>>>(partials, rowptr);
    k_scanC<<<SCAN_BLOCKS, 256, 0, stream>>>(cnt, partials, rowptr);
    hipMemcpyAsync(fill, rowptr, N_NODES * sizeof(int), hipMemcpyDeviceToDevice, stream);
    k_scatter<<<8 * 13 * 125, 256, 0, stream>>>(srcp, dstp, dinv, fill, ssrc, scoef);

    k_gemm1<<<8 * 13 * 32, 256, 0, stream>>>(x, Wa1, Wx1, bufA);
    k_agg128s<<<8 * 13 * 8, 256, 0, stream>>>(bufA, rowptr, ssrc, scoef, dinv, ba1, bx1, bufB);
    k_gemm2<<<8 * 13 * 16, 256, 0, stream>>>(bufB, Wa2, Wx2, bufA);
    k_agg64s<<<8 * 13 * 4, 256, 0, stream>>>(bufA, rowptr, ssrc, scoef, dinv, ba2, bx2, bufB);
    k_smax<<<8 * 13, 256, 0, stream>>>(bufB, gmax, sinv);
    k_pool<<<8 * 13 * 4, 256, 0, stream>>>(bufB, gmax, prods);
    k_head<<<8 * 13, 256, 0, stream>>>(prods, sinv, Wlin, blin, out);
}